// Round 5
// baseline (169.932 us; speedup 1.0000x reference)
//
#include <hip/hip_runtime.h>

#define C_CH 256
#define T_SZ 16
#define H_SZ 64
#define W_SZ 64
#define TGN 5
#define CH 8
#define HWs (H_SZ * W_SZ)          // 4096
#define CSTR (T_SZ * HWs)          // 65536
#define NOUT 196

__device__ __forceinline__ float2 ld2(const float* p) {
    float2 v;
    __builtin_memcpy(&v, p, sizeof(float2));
    return v;
}

__global__ __launch_bounds__(256, 8) void roialign3d_kernel(
    const float* __restrict__ features,
    const float* __restrict__ rois,
    float* __restrict__ out)
{
    // XCD-phased decode: 4 super-rounds x (1024 rois x 8 chunk-lanes).
    // Each XCD sees one 8-channel x 2-batch slab (4 MB = its L2) per round.
    const int bid   = blockIdx.x;
    const int sr    = bid >> 13;
    const int rem   = bid & 8191;
    const int r     = rem >> 3;
    const int chunk = (sr << 3) | (rem & 7);
    const int c0    = chunk * CH;

    const int tid  = threadIdx.x;
    const int lane = tid & 63;
    const int wid  = __builtin_amdgcn_readfirstlane(tid >> 6);  // uniform
    const int hg   = lane >> 3;    // fixed (h,w) grid point per lane
    const int wg   = lane & 7;

    const float* roi = rois + r * 7;
    const int   b   = __builtin_amdgcn_readfirstlane((int)roi[0]);
    const float rx1 = roi[1], ry1 = roi[2], rt1 = roi[3];
    const float rx2 = roi[4], ry2 = roi[5], rt2 = roi[6];

    // ---- per-lane h axis ----
    const float hs = ry1 * 0.0625f, he = ry2 * 0.0625f;
    const float hbin = fmaxf(he - hs, 0.0f) * (1.0f / 7.0f);
    const float hc  = hs + hbin * (float)hg;
    const float hlo = fminf(fmaxf(floorf(hc), 0.0f), 62.0f);
    const float hf  = hc - hlo;
    const float hv  = (hc >= 0.0f && hc < 64.0f) ? 1.0f : 0.0f;
    const int   h0  = (int)hlo;
    const float hw0 = hv * (1.0f - hf), hw1 = hv * hf;

    // ---- per-lane w axis ----
    const float wss = rx1 * 0.0625f, wee = rx2 * 0.0625f;
    const float wbin = fmaxf(wee - wss, 0.0f) * (1.0f / 7.0f);
    const float wc  = wss + wbin * (float)wg;
    const float wlo = fminf(fmaxf(floorf(wc), 0.0f), 62.0f);
    const float wf  = wc - wlo;
    const float wv  = (wc >= 0.0f && wc < 64.0f) ? 1.0f : 0.0f;
    const int   w0  = (int)wlo;
    const float ww0 = wv * (1.0f - wf), ww1 = wv * wf;

    // combined bilinear weights (loop-invariant, per-lane)
    const float w00 = hw0 * ww0, w01 = hw0 * ww1;
    const float w10 = hw1 * ww0, w11 = hw1 * ww1;
    const int hw_off = h0 * W_SZ + w0;          // the ONLY per-lane address part

    // ---- t table: uniform across block -> force scalar ----
    const float tbin = fmaxf(rt2 - rt1, 0.0f) * 0.25f;
    int t0a[TGN]; float tw0a[TGN], tw1a[TGN];
    #pragma unroll
    for (int i = 0; i < TGN; ++i) {
        float c  = rt1 + tbin * (float)i;
        float lo = fminf(fmaxf(floorf(c), 0.0f), 14.0f);
        float f  = c - lo;
        float v  = (c >= 0.0f && c < 16.0f) ? 1.0f : 0.0f;
        t0a[i]  = __builtin_amdgcn_readfirstlane((int)lo);
        tw0a[i] = v * (1.0f - f);
        tw1a[i] = v * f;
    }

    const bool active = (hg < 7) && (wg < 7);
    const int  s_hw   = hg * 7 + wg;

    #pragma unroll
    for (int ccl = 0; ccl < 2; ++ccl) {
        const int cc = wid * 2 + ccl;
        // wave-uniform channel base (SGPR); per-lane part is hw_off only
        const float* fc = features + ((size_t)b * C_CH + (size_t)(c0 + cc)) * CSTR;

        // ---- 20 independent gathers: 5 t-levels x 2 slices x 2 rows ----
        float bl[TGN], bh[TGN];
        #pragma unroll
        for (int tg = 0; tg < TGN; ++tg) {
            const float* p0 = fc + t0a[tg] * HWs + hw_off;
            float2 a0 = ld2(p0);
            float2 a1 = ld2(p0 + W_SZ);
            float2 b0 = ld2(p0 + HWs);
            float2 b1 = ld2(p0 + HWs + W_SZ);
            bl[tg] = a0.x * w00 + a0.y * w01 + a1.x * w10 + a1.y * w11;
            bh[tg] = b0.x * w00 + b0.y * w01 + b1.x * w10 + b1.y * w11;
        }

        float s[TGN];
        #pragma unroll
        for (int tg = 0; tg < TGN; ++tg)
            s[tg] = tw0a[tg] * bl[tg] + tw1a[tg] * bh[tg];

        // ---- pool: T in registers, W/H via shuffles; masked store ----
        float* ob = out + ((size_t)r * C_CH + (c0 + cc)) * NOUT;
        #pragma unroll
        for (int td = 0; td < 4; ++td) {
            float o = s[td] + s[td + 1];
            o += __shfl_down(o, 1);   // + (hg, wg+1)
            o += __shfl_down(o, 8);   // + (hg+1, *)
            if (active)
                __builtin_nontemporal_store(0.125f * o, &ob[td * 49 + s_hw]);
        }
    }
}

extern "C" void kernel_launch(void* const* d_in, const int* in_sizes, int n_in,
                              void* d_out, int out_size, void* d_ws, size_t ws_size,
                              hipStream_t stream) {
    const float* features = (const float*)d_in[0];
    const float* rois     = (const float*)d_in[1];
    float* out            = (float*)d_out;

    int R = in_sizes[1] / 7;   // 1024
    int nblocks = R * (C_CH / CH);
    hipLaunchKernelGGL(roialign3d_kernel, dim3(nblocks), dim3(256), 0, stream,
                       features, rois, out);
}

// Round 6
// 135.101 us; speedup vs baseline: 1.2578x; 1.2578x over previous
//
#include <hip/hip_runtime.h>

#define C_CH 256
#define T_SZ 16
#define H_SZ 64
#define W_SZ 64
#define TGN 5
#define CH 8
#define HWs (H_SZ * W_SZ)          // 4096
#define CSTR (T_SZ * HWs)          // 65536
#define NOUT 196
#define KMAX 10                    // max unique t-slices (t-span <= 7.5)

__device__ __forceinline__ float2 ld2(const float* p) {
    float2 v;
    __builtin_memcpy(&v, p, sizeof(float2));
    return v;
}

__global__ __launch_bounds__(256, 8) void roialign3d_kernel(
    const float* __restrict__ features,
    const float* __restrict__ rois,
    float* __restrict__ out)
{
    // XCD-phased decode: 4 super-rounds x (1024 rois x 8 chunk-lanes).
    // Each XCD sees one 8-channel x 2-batch slab (4 MB = its L2) per round.
    const int bid   = blockIdx.x;
    const int sr    = bid >> 13;
    const int rem   = bid & 8191;
    const int r     = rem >> 3;
    const int chunk = (sr << 3) | (rem & 7);
    const int c0    = chunk * CH;

    const int tid  = threadIdx.x;
    const int lane = tid & 63;
    const int wid  = __builtin_amdgcn_readfirstlane(tid >> 6);
    const int hg   = lane >> 3;    // fixed (h,w) grid point per lane
    const int wg   = lane & 7;

    const float* roi = rois + r * 7;
    const int   b   = __builtin_amdgcn_readfirstlane((int)roi[0]);
    const float rx1 = roi[1], ry1 = roi[2], rt1 = roi[3];
    const float rx2 = roi[4], ry2 = roi[5], rt2 = roi[6];

    // ---- per-lane h axis ----
    const float hs = ry1 * 0.0625f, he = ry2 * 0.0625f;
    const float hbin = fmaxf(he - hs, 0.0f) * (1.0f / 7.0f);
    const float hc  = hs + hbin * (float)hg;
    const float hlo = fminf(fmaxf(floorf(hc), 0.0f), 62.0f);
    const float hf  = hc - hlo;
    const float hv  = (hc >= 0.0f && hc < 64.0f) ? 1.0f : 0.0f;
    const int   h0  = (int)hlo;
    const float hw0 = hv * (1.0f - hf), hw1 = hv * hf;

    // ---- per-lane w axis ----
    const float wss = rx1 * 0.0625f, wee = rx2 * 0.0625f;
    const float wbin = fmaxf(wee - wss, 0.0f) * (1.0f / 7.0f);
    const float wc  = wss + wbin * (float)wg;
    const float wlo = fminf(fmaxf(floorf(wc), 0.0f), 62.0f);
    const float wf  = wc - wlo;
    const float wv  = (wc >= 0.0f && wc < 64.0f) ? 1.0f : 0.0f;
    const int   w0  = (int)wlo;
    const float ww0 = wv * (1.0f - wf), ww1 = wv * wf;

    // combined bilinear weights (loop-invariant, per-lane)
    const float w00 = hw0 * ww0, w01 = hw0 * ww1;
    const float w10 = hw1 * ww0, w11 = hw1 * ww1;
    const int hw_off = h0 * W_SZ + w0;          // only per-lane address part

    // ---- t table: scalar indices, 0.125-prefolded weights ----
    const float tbin = fmaxf(rt2 - rt1, 0.0f) * 0.25f;
    int t0a[TGN]; float tw0a[TGN], tw1a[TGN];
    #pragma unroll
    for (int i = 0; i < TGN; ++i) {
        float c  = rt1 + tbin * (float)i;
        float lo = fminf(fmaxf(floorf(c), 0.0f), 14.0f);
        float f  = c - lo;
        float v  = (c >= 0.0f && c < 16.0f) ? 0.125f : 0.0f;   // validity * 1/8
        t0a[i]  = __builtin_amdgcn_readfirstlane((int)lo);
        tw0a[i] = v * (1.0f - f);
        tw1a[i] = v * f;
    }
    const int u0   = t0a[0];
    const int kcnt = t0a[TGN - 1] + 2 - u0;    // scalar, in [2, 10]

    const bool active = (hg < 7) && (wg < 7);
    const int  s_hw   = hg * 7 + wg;

    // wave-uniform channel bases (SGPR)
    const float* fcA = features + ((size_t)b * C_CH + (size_t)(c0 + wid * 2)) * CSTR
                     + (size_t)u0 * HWs;
    const float* fcB = fcA + CSTR;

    float oA[4] = {0.f, 0.f, 0.f, 0.f};
    float oB[4] = {0.f, 0.f, 0.f, 0.f};

    #pragma unroll
    for (int u = 0; u < KMAX; ++u) {
        if (u < 2 || u < kcnt) {               // u=0,1 always valid (kcnt>=2)
            // per-slice folded T-interp + T-pool coefficients (uniform)
            float a0, a1, a2, a3, a4;
            {
                const int s0 = u0 + u;
                a0 = (t0a[0] == s0 ? tw0a[0] : 0.f) + (t0a[0] + 1 == s0 ? tw1a[0] : 0.f);
                a1 = (t0a[1] == s0 ? tw0a[1] : 0.f) + (t0a[1] + 1 == s0 ? tw1a[1] : 0.f);
                a2 = (t0a[2] == s0 ? tw0a[2] : 0.f) + (t0a[2] + 1 == s0 ? tw1a[2] : 0.f);
                a3 = (t0a[3] == s0 ? tw0a[3] : 0.f) + (t0a[3] + 1 == s0 ? tw1a[3] : 0.f);
                a4 = (t0a[4] == s0 ? tw0a[4] : 0.f) + (t0a[4] + 1 == s0 ? tw1a[4] : 0.f);
            }
            const float b0 = a0 + a1, b1 = a1 + a2, b2 = a2 + a3, b3 = a3 + a4;

            // one unique slice: 2 gathers per channel, both channels interleaved
            const float* pA = fcA + u * HWs + hw_off;
            const float* pB = fcB + u * HWs + hw_off;
            float2 rA0 = ld2(pA);
            float2 rA1 = ld2(pA + W_SZ);
            float2 rB0 = ld2(pB);
            float2 rB1 = ld2(pB + W_SZ);

            const float bilA = rA0.x * w00 + rA0.y * w01 + rA1.x * w10 + rA1.y * w11;
            const float bilB = rB0.x * w00 + rB0.y * w01 + rB1.x * w10 + rB1.y * w11;

            oA[0] += b0 * bilA; oA[1] += b1 * bilA; oA[2] += b2 * bilA; oA[3] += b3 * bilA;
            oB[0] += b0 * bilB; oB[1] += b1 * bilB; oB[2] += b2 * bilB; oB[3] += b3 * bilB;
        }
    }

    // ---- pool W/H via shuffles; masked nontemporal store (x2 channels) ----
    {
        float* ob = out + ((size_t)r * C_CH + (size_t)(c0 + wid * 2)) * NOUT;
        #pragma unroll
        for (int td = 0; td < 4; ++td) {
            float o = oA[td];
            o += __shfl_down(o, 1);
            o += __shfl_down(o, 8);
            if (active) __builtin_nontemporal_store(o, &ob[td * 49 + s_hw]);
        }
        ob += NOUT;
        #pragma unroll
        for (int td = 0; td < 4; ++td) {
            float o = oB[td];
            o += __shfl_down(o, 1);
            o += __shfl_down(o, 8);
            if (active) __builtin_nontemporal_store(o, &ob[td * 49 + s_hw]);
        }
    }
}

extern "C" void kernel_launch(void* const* d_in, const int* in_sizes, int n_in,
                              void* d_out, int out_size, void* d_ws, size_t ws_size,
                              hipStream_t stream) {
    const float* features = (const float*)d_in[0];
    const float* rois     = (const float*)d_in[1];
    float* out            = (float*)d_out;

    int R = in_sizes[1] / 7;   // 1024
    int nblocks = R * (C_CH / CH);
    hipLaunchKernelGGL(roialign3d_kernel, dim3(nblocks), dim3(256), 0, stream,
                       features, rois, out);
}

// Round 7
// 133.478 us; speedup vs baseline: 1.2731x; 1.0122x over previous
//
#include <hip/hip_runtime.h>

#define C_CH 256
#define T_SZ 16
#define H_SZ 64
#define W_SZ 64
#define TGN 5
#define CH 8
#define HWs (H_SZ * W_SZ)          // 4096
#define CSTR (T_SZ * HWs)          // 65536
#define NOUT 196
#define KMAX 10                    // max unique t-slices

__device__ __forceinline__ float2 ld2(const float* p) {
    float2 v;
    __builtin_memcpy(&v, p, sizeof(float2));
    return v;
}

__global__ __launch_bounds__(256, 8) void roialign3d_kernel(
    const float* __restrict__ features,
    const float* __restrict__ rois,
    float* __restrict__ out)
{
    // XCD-phased decode: 4 super-rounds x (1024 rois x 8 chunk-lanes).
    const int bid   = blockIdx.x;
    const int sr    = bid >> 13;
    const int rem   = bid & 8191;
    const int r     = rem >> 3;
    const int chunk = (sr << 3) | (rem & 7);
    const int c0    = chunk * CH;

    const int tid  = threadIdx.x;
    const int lane = tid & 63;
    const int wid  = __builtin_amdgcn_readfirstlane(tid >> 6);
    const int hg   = lane >> 3;    // fixed (h,w) grid point per lane
    const int wg   = lane & 7;

    __shared__ __align__(16) float sB[KMAX][4];   // pooled-T coeff per slice
    __shared__ int sU0, sK;

    const float* roi = rois + r * 7;
    const int   b   = __builtin_amdgcn_readfirstlane((int)roi[0]);
    const float rx1 = roi[1], ry1 = roi[2];
    const float rx2 = roi[4], ry2 = roi[5];

    // ---- t-coefficient table: built once by threads 0..9 (wave 0 only) ----
    if (tid < KMAX) {
        const float rt1 = roi[3], rt2 = roi[6];
        const float tbin = fmaxf(rt2 - rt1, 0.0f) * 0.25f;
        int t0a[TGN]; float tw0a[TGN], tw1a[TGN];
        #pragma unroll
        for (int i = 0; i < TGN; ++i) {
            float c  = rt1 + tbin * (float)i;
            float lo = fminf(fmaxf(floorf(c), 0.0f), 14.0f);
            float f  = c - lo;
            float v  = (c >= 0.0f && c < 16.0f) ? 0.125f : 0.0f;  // valid * 1/8
            t0a[i]  = (int)lo;
            tw0a[i] = v * (1.0f - f);
            tw1a[i] = v * f;
        }
        const int u0 = t0a[0];
        const int s0 = u0 + tid;
        float av[TGN];
        #pragma unroll
        for (int i = 0; i < TGN; ++i)
            av[i] = (t0a[i] == s0 ? tw0a[i] : 0.0f)
                  + (t0a[i] + 1 == s0 ? tw1a[i] : 0.0f);
        sB[tid][0] = av[0] + av[1];
        sB[tid][1] = av[1] + av[2];
        sB[tid][2] = av[2] + av[3];
        sB[tid][3] = av[3] + av[4];
        if (tid == 0) { sU0 = u0; sK = t0a[TGN - 1] + 2 - u0; }
    }

    // ---- per-lane h axis ----
    const float hs = ry1 * 0.0625f, he = ry2 * 0.0625f;
    const float hbin = fmaxf(he - hs, 0.0f) * (1.0f / 7.0f);
    const float hc  = hs + hbin * (float)hg;
    const float hlo = fminf(fmaxf(floorf(hc), 0.0f), 62.0f);
    const float hf  = hc - hlo;
    const float hv  = (hc >= 0.0f && hc < 64.0f) ? 1.0f : 0.0f;
    const int   h0  = (int)hlo;
    const float hw0 = hv * (1.0f - hf), hw1 = hv * hf;

    // ---- per-lane w axis ----
    const float wss = rx1 * 0.0625f, wee = rx2 * 0.0625f;
    const float wbin = fmaxf(wee - wss, 0.0f) * (1.0f / 7.0f);
    const float wc  = wss + wbin * (float)wg;
    const float wlo = fminf(fmaxf(floorf(wc), 0.0f), 62.0f);
    const float wf  = wc - wlo;
    const float wv  = (wc >= 0.0f && wc < 64.0f) ? 1.0f : 0.0f;
    const int   w0  = (int)wlo;
    const float ww0 = wv * (1.0f - wf), ww1 = wv * wf;

    const float w00 = hw0 * ww0, w01 = hw0 * ww1;
    const float w10 = hw1 * ww0, w11 = hw1 * ww1;
    const int hw_off = h0 * W_SZ + w0;

    __syncthreads();
    const int u0   = __builtin_amdgcn_readfirstlane(sU0);
    const int kcnt = __builtin_amdgcn_readfirstlane(sK);   // in [2, 10]

    const bool active = (hg < 7) && (wg < 7);
    const int  s_hw   = hg * 7 + wg;

    const float* fcA = features
        + ((size_t)b * C_CH + (size_t)(c0 + wid * 2)) * CSTR
        + (size_t)u0 * HWs + hw_off;
    const float* fcB = fcA + CSTR;

    float oA[4] = {0.f, 0.f, 0.f, 0.f};
    float oB[4] = {0.f, 0.f, 0.f, 0.f};

    #pragma unroll
    for (int u = 0; u < KMAX; ++u) {
        if (u < 2 || u < kcnt) {               // scalar branch (kcnt >= 2)
            const float4 bb = *(const float4*)sB[u];   // uniform broadcast
            const float* pA = fcA + u * HWs;
            const float* pB = fcB + u * HWs;
            float2 rA0 = ld2(pA);
            float2 rA1 = ld2(pA + W_SZ);
            float2 rB0 = ld2(pB);
            float2 rB1 = ld2(pB + W_SZ);

            const float bilA = rA0.x * w00 + rA0.y * w01 + rA1.x * w10 + rA1.y * w11;
            const float bilB = rB0.x * w00 + rB0.y * w01 + rB1.x * w10 + rB1.y * w11;

            oA[0] += bb.x * bilA; oA[1] += bb.y * bilA;
            oA[2] += bb.z * bilA; oA[3] += bb.w * bilA;
            oB[0] += bb.x * bilB; oB[1] += bb.y * bilB;
            oB[2] += bb.z * bilB; oB[3] += bb.w * bilB;
        }
    }

    // ---- pool W/H via shuffles; masked nontemporal store (x2 channels) ----
    float* ob = out + ((size_t)r * C_CH + (size_t)(c0 + wid * 2)) * NOUT;
    #pragma unroll
    for (int td = 0; td < 4; ++td) {
        float o = oA[td];
        o += __shfl_down(o, 1);
        o += __shfl_down(o, 8);
        if (active) __builtin_nontemporal_store(o, &ob[td * 49 + s_hw]);
    }
    ob += NOUT;
    #pragma unroll
    for (int td = 0; td < 4; ++td) {
        float o = oB[td];
        o += __shfl_down(o, 1);
        o += __shfl_down(o, 8);
        if (active) __builtin_nontemporal_store(o, &ob[td * 49 + s_hw]);
    }
}

extern "C" void kernel_launch(void* const* d_in, const int* in_sizes, int n_in,
                              void* d_out, int out_size, void* d_ws, size_t ws_size,
                              hipStream_t stream) {
    const float* features = (const float*)d_in[0];
    const float* rois     = (const float*)d_in[1];
    float* out            = (float*)d_out;

    int R = in_sizes[1] / 7;   // 1024
    int nblocks = R * (C_CH / CH);
    hipLaunchKernelGGL(roialign3d_kernel, dim3(nblocks), dim3(256), 0, stream,
                       features, rois, out);
}